// Round 7
// baseline (4001.854 us; speedup 1.0000x reference)
//
#include <hip/hip_runtime.h>
#include <hip/hip_fp16.h>
#include <cstddef>

#define NMOD 64
#define HID 512
#define TSTEPS 1024
#define G4 2048           // gate rows per module

// ws layout: NO weight buffer anymore (weights converted in-register at load)
#define WOFF_PERMOD 0            // 64*4 f32 per-block partial outputs
#define WOFF_HX     8192         // [2][64][4 dest][4 src][512] u64 = 8 MB
#define HX_WORDS    (2ull * NMOD * 4 * 4 * 512)
#define WS_NEED     (WOFF_HX + HX_WORDS * 8ull)

typedef _Float16 h2_t __attribute__((ext_vector_type(2)));
union U32H2 { unsigned u; h2_t h; };
__device__ __forceinline__ h2_t u2h(unsigned u) { U32H2 x; x.u = u; return x.h; }

#if __has_builtin(__builtin_amdgcn_fdot2)
#define FDOT2(a, b, c) __builtin_amdgcn_fdot2((a), (b), (c), false)
#else
__device__ __forceinline__ float FDOT2(h2_t a, h2_t b, float c) {
    return c + (float)a[0] * (float)b[0] + (float)a[1] * (float)b[1];
}
#endif

__device__ __forceinline__ float fsig(float x)  { return 1.0f / (1.0f + __expf(-x)); }
__device__ __forceinline__ float ftanh_(float x){ return 1.0f - 2.0f / (__expf(2.0f * x) + 1.0f); }

// DPP lane-xor within 16-lane rows (VALU pipe, not LDS pipe).
// quad_perm xor1 = 0xB1, xor2 = 0x4E; ROW_HALF_MIRROR(xor4)=0x141; ROW_MIRROR(xor8)=0x140
template<int CTRL>
__device__ __forceinline__ float dppf(float x) {
    int xi = __builtin_bit_cast(int, x);
    int r = __builtin_amdgcn_update_dpp(0, xi, CTRL, 0xF, 0xF, true);
    return __builtin_bit_cast(float, r);
}

__device__ __forceinline__ uint4 pack8(const float* p) {
    const float4 a = *reinterpret_cast<const float4*>(p);
    const float4 c = *reinterpret_cast<const float4*>(p + 4);
    __half2 h0 = __floats2half2_rn(a.x, a.y);
    __half2 h1 = __floats2half2_rn(a.z, a.w);
    __half2 h2 = __floats2half2_rn(c.x, c.y);
    __half2 h3 = __floats2half2_rn(c.z, c.w);
    uint4 o;
    o.x = *reinterpret_cast<unsigned*>(&h0);
    o.y = *reinterpret_cast<unsigned*>(&h1);
    o.z = *reinterpret_cast<unsigned*>(&h2);
    o.w = *reinterpret_cast<unsigned*>(&h3);
    return o;
}

__device__ __forceinline__ float dot4(uint4 wv, uint4 hv, float acc) {
    acc = FDOT2(u2h(wv.x), u2h(hv.x), acc);
    acc = FDOT2(u2h(wv.y), u2h(hv.y), acc);
    acc = FDOT2(u2h(wv.z), u2h(hv.z), acc);
    acc = FDOT2(u2h(wv.w), u2h(hv.w), acc);
    return acc;
}

// ---------------- column-split weights-resident LSTM -------------------------
// 4 blocks/module, 512 thr, 1 block/CU. Block b owns h elems [128b,128b+128)
// AND weight cols [128b,128b+128) for ALL 2048 gate rows -> every dot is
// local. Exchange carries f32 ROW PARTIALS (seq-tagged u64, parity dbuf).
// Thread (rg=tid>>4, cg=tid&15): rows [rg*64,+64) x cols b*128+cg*8..+8.
// Quarters Q=0..2 in VGPRs (192 u32), Q=3 in LDS. Per-quarter DPP butterfly
// lands row rg*64+Q*16+rev4(cg) on lane cg; dest block ob=(rg>>1)&3 is
// uniform per 16-lane group. Exports fire per-quarter (pipelined arrival).
__global__ __launch_bounds__(512, 2) void lstm_col_kernel(
    const float* __restrict__ history,
    const float* __restrict__ W_ih,
    const float* __restrict__ W_hh,
    const float* __restrict__ b_ih,
    const float* __restrict__ b_hh,
    const float* __restrict__ lin_W,
    unsigned long long* hx,             // [2][64][4][4][512] tagged partials
    float* __restrict__ per_mod4)       // [64][4]
{
    // XCD remap: module's 4 blocks share bid&7 -> same XCD under round-robin
    const int bid = blockIdx.x;
    const int m = (bid & 7) * 8 + (bid >> 5);
    const int b = (bid >> 3) & 3;
    const int tid = threadIdx.x;
    const int rg = tid >> 4;   // 0..31
    const int cg = tid & 15;   // 0..15

    __shared__ unsigned w_lds[32768];   // 128 KB: [(rg*16+u)][cg] uint4
    __shared__ float part_lds[512];     // own-row local partials
    __shared__ float gates_sh[512];     // activated gates
    __shared__ unsigned h_u32[64];      // my 128 h elems as f16 pairs
    __shared__ float hist_sh[TSTEPS];
    __shared__ float red_sh[8];

    for (int i = tid; i < TSTEPS; i += 512)
        hist_sh[i] = history[(size_t)m * TSTEPS + i];
    if (tid < 64) h_u32[tid] = 0u;

    // ---- load + convert weights: rows rg*64+r, cols b*128+cg*8..+8 ----
    const float* wmB = W_hh + (size_t)m * G4 * HID + (size_t)(b * 128 + cg * 8);
    uint4 w[3][16];
    #pragma unroll
    for (int Q = 0; Q < 3; ++Q)
        #pragma unroll
        for (int u = 0; u < 16; ++u)
            w[Q][u] = pack8(wmB + (size_t)(rg * 64 + Q * 16 + u) * HID);
    #pragma unroll
    for (int u = 0; u < 16; ++u)
        *(uint4*)&w_lds[((rg * 16 + u) * 16 + cg) * 4] =
            pack8(wmB + (size_t)(rg * 64 + 48 + u) * HID);

    // import-phase constants: thread tid owns destination row dr=tid,
    // global row gri = (tid>>7)*512 + b*128 + (tid&127)
    const int gri = (tid >> 7) * 512 + b * 128 + (tid & 127);
    const float wib_i  = W_ih[(size_t)m * G4 + gri];
    const float bias_i = b_ih[(size_t)m * G4 + gri] + b_hh[(size_t)m * G4 + gri];

    // export geometry (uniform per 16-lane group)
    const int rev = ((cg & 1) << 3) | ((cg & 2) << 1) | ((cg & 4) >> 1) | ((cg & 8) >> 3);
    const int ob  = (rg >> 1) & 3;                       // dest block of my rows
    const bool own = (ob == b);
    const int drb = ((rg >> 3) << 7) + ((rg & 1) << 6) + rev;  // + Q*16
    const int s0 = (b + 1) & 3, s1 = (b + 2) & 3, s2 = (b + 3) & 3;

    float c_reg = 0.0f;   // cell state, lives in tid<128
    __syncthreads();

    for (int t = 0; t < TSTEPS; ++t) {
        const unsigned seq = (unsigned)(t + 1);
        unsigned long long* hxp = hx + ((size_t)(seq & 1) * NMOD + m) * (4 * 4 * 512);

        // ---- dots (all-local h) + per-quarter butterfly + early export ----
        const uint4 hq = *(const uint4*)&h_u32[cg * 4];
        #pragma unroll
        for (int Q = 0; Q < 4; ++Q) {
            float acc[16];
            #pragma unroll
            for (int u = 0; u < 16; ++u) {
                uint4 wv;
                if (Q < 3) wv = w[Q][u];
                else       wv = *(const uint4*)&w_lds[((rg * 16 + u) * 16 + cg) * 4];
                acc[u] = dot4(wv, hq, 0.0f);
            }
            // payload-halving butterfly over cg (DPP, within 16-lane row)
            #pragma unroll
            for (int k = 0; k < 8; ++k) {
                const float send = (cg & 1) ? acc[k] : acc[8 + k];
                const float recv = dppf<0xB1>(send);
                acc[k] = ((cg & 1) ? acc[8 + k] : acc[k]) + recv;
            }
            #pragma unroll
            for (int k = 0; k < 4; ++k) {
                const float send = (cg & 2) ? acc[k] : acc[4 + k];
                const float recv = dppf<0x4E>(send);
                acc[k] = ((cg & 2) ? acc[4 + k] : acc[k]) + recv;
            }
            #pragma unroll
            for (int k = 0; k < 2; ++k) {
                const float send = (cg & 4) ? acc[k] : acc[2 + k];
                const float recv = dppf<0x141>(send);
                acc[k] = ((cg & 4) ? acc[2 + k] : acc[k]) + recv;
            }
            {
                const float send = (cg & 8) ? acc[0] : acc[1];
                const float recv = dppf<0x140>(send);
                acc[0] = ((cg & 8) ? acc[1] : acc[0]) + recv;
            }
            const float S = acc[0];
            const int dr = drb + Q * 16;
            if (own) {
                part_lds[dr] = S;
            } else {
                __hip_atomic_store(&hxp[(size_t)(ob * 4 + b) * 512 + dr],
                                   ((unsigned long long)seq << 32) |
                                   (unsigned long long)__float_as_uint(S),
                                   __ATOMIC_RELAXED, __HIP_MEMORY_SCOPE_AGENT);
            }
        }

        // speculative first polls (overlap store->visibility latency)
        unsigned long long* a0 = &hxp[(size_t)(b * 4 + s0) * 512 + tid];
        unsigned long long* a1 = &hxp[(size_t)(b * 4 + s1) * 512 + tid];
        unsigned long long* a2 = &hxp[(size_t)(b * 4 + s2) * 512 + tid];
        unsigned long long v0 = __hip_atomic_load(a0, __ATOMIC_RELAXED, __HIP_MEMORY_SCOPE_AGENT);
        unsigned long long v1 = __hip_atomic_load(a1, __ATOMIC_RELAXED, __HIP_MEMORY_SCOPE_AGENT);
        unsigned long long v2 = __hip_atomic_load(a2, __ATOMIC_RELAXED, __HIP_MEMORY_SCOPE_AGENT);
        __syncthreads();   // B1: part_lds complete

        // ---- import: sum 4 partials for my row dr=tid; activate ----
        float sum = part_lds[tid];
        while ((unsigned)(v0 >> 32) != seq)
            v0 = __hip_atomic_load(a0, __ATOMIC_RELAXED, __HIP_MEMORY_SCOPE_AGENT);
        while ((unsigned)(v1 >> 32) != seq)
            v1 = __hip_atomic_load(a1, __ATOMIC_RELAXED, __HIP_MEMORY_SCOPE_AGENT);
        while ((unsigned)(v2 >> 32) != seq)
            v2 = __hip_atomic_load(a2, __ATOMIC_RELAXED, __HIP_MEMORY_SCOPE_AGENT);
        sum += __uint_as_float((unsigned)v0);
        sum += __uint_as_float((unsigned)v1);
        sum += __uint_as_float((unsigned)v2);
        const float g = sum + hist_sh[t] * wib_i + bias_i;
        gates_sh[tid] = ((tid >> 7) == 2) ? ftanh_(g) : fsig(g);   // g-gate=tanh
        __syncthreads();   // B2: activated gates ready

        // ---- cell update for my 128 h elems ----
        if (tid < 128) {
            const float gi = gates_sh[tid];
            const float gf = gates_sh[128 + tid];
            const float gg = gates_sh[256 + tid];
            const float go = gates_sh[384 + tid];
            c_reg = gf * c_reg + gi * gg;
            ((__half*)h_u32)[tid] = __float2half(go * ftanh_(c_reg));
        }
        __syncthreads();   // B3: h(t+1) ready
    }

    // ---- per-block partial of the per-module linear ----
    float v = 0.0f;
    if (tid < 128) {
        const float hvf = __half2float(((const __half*)h_u32)[tid]);
        v = hvf * lin_W[(size_t)m * (HID + 1) + b * 128 + tid];
    }
    #pragma unroll
    for (int sft = 32; sft; sft >>= 1) v += __shfl_xor(v, sft, 64);
    if ((tid & 63) == 0) red_sh[tid >> 6] = v;
    __syncthreads();
    if (tid == 0) {
        float s = 0.0f;
        #pragma unroll
        for (int wv2 = 0; wv2 < 8; ++wv2) s += red_sh[wv2];
        per_mod4[m * 4 + b] = s;
    }
}

// ---------------- fallback: round-1 f32 single-block-per-module kernel -------
__global__ __launch_bounds__(1024) void lstm_module_kernel(
    const float* __restrict__ history,
    const float* __restrict__ W_ih,
    const float* __restrict__ W_hh,
    const float* __restrict__ b_ih,
    const float* __restrict__ b_hh,
    const float* __restrict__ lin_W,
    float* __restrict__ per_mod4)
{
    const int n = blockIdx.x;
    const int tid = threadIdx.x;

    __shared__ float h_sh[HID];
    __shared__ float gates_sh[G4];
    __shared__ float wib_sh[G4];
    __shared__ float bias_sh[G4];
    __shared__ float hist_sh[TSTEPS];

    for (int i = tid; i < G4; i += 1024) {
        wib_sh[i]  = W_ih[(size_t)n * G4 + i];
        bias_sh[i] = b_ih[(size_t)n * G4 + i] + b_hh[(size_t)n * G4 + i];
    }
    for (int i = tid; i < TSTEPS; i += 1024) hist_sh[i] = history[(size_t)n * TSTEPS + i];
    if (tid < HID) h_sh[tid] = 0.0f;
    float c_reg = 0.0f;
    __syncthreads();

    const int sub = tid & 15;
    const int rid = tid >> 4;
    const float* Wbase = W_hh + (size_t)n * G4 * HID;

    for (int t = 0; t < TSTEPS; ++t) {
        const float x = hist_sh[t];
        float hreg[32];
        #pragma unroll
        for (int j = 0; j < 8; ++j) {
            const float4 hv = *reinterpret_cast<const float4*>(&h_sh[sub * 4 + j * 64]);
            hreg[4 * j + 0] = hv.x; hreg[4 * j + 1] = hv.y;
            hreg[4 * j + 2] = hv.z; hreg[4 * j + 3] = hv.w;
        }
        for (int p = 0; p < 32; ++p) {
            const int r = p * 64 + rid;
            const float* wr = Wbase + (size_t)r * HID + sub * 4;
            float acc = 0.0f;
            #pragma unroll
            for (int j = 0; j < 8; ++j) {
                const float4 wv = *reinterpret_cast<const float4*>(wr + j * 64);
                acc += wv.x * hreg[4*j+0] + wv.y * hreg[4*j+1]
                     + wv.z * hreg[4*j+2] + wv.w * hreg[4*j+3];
            }
            acc += __shfl_xor(acc, 1, 64);
            acc += __shfl_xor(acc, 2, 64);
            acc += __shfl_xor(acc, 4, 64);
            acc += __shfl_xor(acc, 8, 64);
            if (sub == 0) gates_sh[r] = acc + x * wib_sh[r] + bias_sh[r];
        }
        __syncthreads();
        if (tid < HID) {
            const float ig = fsig(gates_sh[tid]);
            const float fg = fsig(gates_sh[HID + tid]);
            const float gg = ftanh_(gates_sh[2 * HID + tid]);
            const float og = fsig(gates_sh[3 * HID + tid]);
            c_reg = fg * c_reg + ig * gg;
            h_sh[tid] = og * ftanh_(c_reg);
        }
        __syncthreads();
    }

    if (tid < HID) {
        float v = h_sh[tid] * lin_W[(size_t)n * (HID + 1) + tid];
        #pragma unroll
        for (int m2 = 32; m2; m2 >>= 1) v += __shfl_xor(v, m2, 64);
        if ((tid & 63) == 0) gates_sh[tid >> 6] = v;
    }
    __syncthreads();
    if (tid == 0) {
        float s = 0.0f;
        #pragma unroll
        for (int w = 0; w < HID / 64; ++w) s += gates_sh[w];
        per_mod4[n * 4] = s;   // slots 1..3 stay zero (ws memset)
    }
}

__global__ void finish_kernel(const float* __restrict__ per_mod4,
                              const float* __restrict__ recent,
                              const float* __restrict__ lin_W,
                              const float* __restrict__ lin_b,
                              const float* __restrict__ final_W,
                              const float* __restrict__ final_b,
                              float* __restrict__ out)
{
    const int l = threadIdx.x;   // 64 threads, one module each
    float s = per_mod4[l * 4 + 0] + per_mod4[l * 4 + 1]
            + per_mod4[l * 4 + 2] + per_mod4[l * 4 + 3]
            + recent[l] * lin_W[(size_t)l * (HID + 1) + HID] + lin_b[l];
    float v = s * final_W[l];
    #pragma unroll
    for (int m = 32; m; m >>= 1) v += __shfl_xor(v, m, 64);
    if (l == 0) out[0] = v + final_b[0];
}

extern "C" void kernel_launch(void* const* d_in, const int* in_sizes, int n_in,
                              void* d_out, int out_size, void* d_ws, size_t ws_size,
                              hipStream_t stream) {
    const float* recent  = (const float*)d_in[0];
    const float* history = (const float*)d_in[1];
    const float* W_ih    = (const float*)d_in[2];
    const float* W_hh    = (const float*)d_in[3];
    const float* b_ih    = (const float*)d_in[4];
    const float* b_hh    = (const float*)d_in[5];
    const float* lin_W   = (const float*)d_in[6];
    const float* lin_b   = (const float*)d_in[7];
    const float* final_W = (const float*)d_in[8];
    const float* final_b = (const float*)d_in[9];
    float* out = (float*)d_out;
    float* per_mod4 = (float*)d_ws;

    // zero per_mod4 + hx tags each call (ws is not re-poisoned between replays)
    hipMemsetAsync(d_ws, 0, WS_NEED, stream);

    if (ws_size >= WS_NEED) {
        unsigned long long* hx = (unsigned long long*)((char*)d_ws + WOFF_HX);
        lstm_col_kernel<<<NMOD * 4, 512, 0, stream>>>(
            history, W_ih, W_hh, b_ih, b_hh, lin_W, hx, per_mod4);
    } else {
        lstm_module_kernel<<<NMOD, 1024, 0, stream>>>(
            history, W_ih, W_hh, b_ih, b_hh, lin_W, per_mod4);
    }
    finish_kernel<<<1, 64, 0, stream>>>(per_mod4, recent, lin_W, lin_b,
                                        final_W, final_b, out);
}

// Round 8
// 2439.930 us; speedup vs baseline: 1.6402x; 1.6402x over previous
//
#include <hip/hip_runtime.h>
#include <hip/hip_fp16.h>
#include <cstddef>

#define NMOD 64
#define HID 512
#define TSTEPS 1024
#define G4 2048           // gate rows per module

// ws layout
#define WOFF_PERMOD 0            // 64 f32
#define WOFF_HX     16384        // 2*64*256 u64 seq-tagged h pairs = 256 KB
#define WOFF_W16    524288       // 64*2048*512 f16 = 128 MB
#define W16_BYTES   ((size_t)NMOD * G4 * HID * 2)
#define WS_NEED     (WOFF_W16 + W16_BYTES)

__device__ __forceinline__ float fsig(float x)  { return 1.0f / (1.0f + __expf(-x)); }
__device__ __forceinline__ float ftanh_(float x){ return 1.0f - 2.0f / (__expf(2.0f * x) + 1.0f); }

// dot2 via inline asm with "v" constraints: pins operands to the ARCH VGPR
// class so the 192-reg weight tile cannot be banked in AGPRs (which cost one
// v_accvgpr_read per use -- the measured ~2x VALU inflation of R5/R6).
__device__ __forceinline__ float adot2(unsigned a, unsigned b, float c) {
    float d;
    asm("v_dot2_f32_f16 %0, %1, %2, %3" : "=v"(d) : "v"(a), "v"(b), "v"(c));
    return d;
}
__device__ __forceinline__ float dot4(uint4 wv, uint4 hv, float acc) {
    acc = adot2(wv.x, hv.x, acc);
    acc = adot2(wv.y, hv.y, acc);
    acc = adot2(wv.z, hv.z, acc);
    acc = adot2(wv.w, hv.w, acc);
    return acc;
}

// DPP lane-xor within quads (VALU pipe, 2-cy): 0xB1 = xor1, 0x4E = xor2.
template<int CTRL>
__device__ __forceinline__ float dppf(float x) {
    int xi = __builtin_bit_cast(int, x);
    int r = __builtin_amdgcn_update_dpp(0, xi, CTRL, 0xF, 0xF, true);
    return __builtin_bit_cast(float, r);
}

// ---------------- f32 -> f16 weight conversion ------------------------------
__global__ __launch_bounds__(256) void conv_kernel(const float* __restrict__ src,
                                                   __half* __restrict__ dst) {
    const size_t i = ((size_t)blockIdx.x * 256 + threadIdx.x) * 8;
    const float4 a = *reinterpret_cast<const float4*>(src + i);
    const float4 b = *reinterpret_cast<const float4*>(src + i + 4);
    __half2 h0 = __floats2half2_rn(a.x, a.y);
    __half2 h1 = __floats2half2_rn(a.z, a.w);
    __half2 h2 = __floats2half2_rn(b.x, b.y);
    __half2 h3 = __floats2half2_rn(b.z, b.w);
    uint4 o;
    o.x = *reinterpret_cast<unsigned*>(&h0);
    o.y = *reinterpret_cast<unsigned*>(&h1);
    o.z = *reinterpret_cast<unsigned*>(&h2);
    o.w = *reinterpret_cast<unsigned*>(&h3);
    *reinterpret_cast<uint4*>(dst + i) = o;
}

// ---------------- weights-resident LSTM (R5 structure + arch-VGPR dots) -----
// 4 blocks/module, 512 thr, 1 block/CU. Thread (rg=tid>>4, cg=tid&15) owns
// 16 local rows x cols [cg*32,(cg+1)*32); kk-th 8-col chunk from h REGION
// (b+kk)&3 (kk=0 local). Rows 0-11 in ARCH VGPRs (asm-pinned), 12-15 in LDS.
// Butterfly: stages 1-2 DPP quad_perm (true xor), stages 3-4 shfl_xor.
// Cell spread over tid<128 (1 elem each); exchange protocol = R5 verbatim.
__global__ __launch_bounds__(512, 2) void lstm_res_kernel(
    const float* __restrict__ recent,
    const float* __restrict__ history,
    const float* __restrict__ W_ih,
    const float* __restrict__ b_ih,
    const float* __restrict__ b_hh,
    const float* __restrict__ lin_W,
    const float* __restrict__ lin_b,
    const unsigned* __restrict__ w16u,  // f16 weights as u32 pairs
    unsigned long long* hx,             // [2][64][256] seq-tagged pairs, zeroed
    float* __restrict__ per_mod)        // [64]
{
    // XCD-grouping remap: module's 4 blocks share bid&7 -> same XCD under RR
    const int bid = blockIdx.x;
    const int m = (bid & 7) * 8 + (bid >> 5);
    const int b = (bid >> 3) & 3;
    const int tid = threadIdx.x;
    const int rg = tid >> 4;   // 0..31
    const int cg = tid & 15;   // 0..15

    __shared__ unsigned w_lds[32768];   // 128 KB: [rg*4+r2][64 chunks][4 u32]
    __shared__ unsigned h_pk[256];      // full h as packed f16x2, linear pairs
    __shared__ float gates_sh[512];
    __shared__ float hist_sh[TSTEPS];
    __shared__ float red_sh[8];

    for (int i = tid; i < TSTEPS; i += 512)
        hist_sh[i] = history[(size_t)m * TSTEPS + i];

    // ---- load resident weights (region-interleaved chunk mapping) ----
    const size_t rowbase = (size_t)m * G4 * 256;   // u32 units, row stride 256
    uint4 w[12][4];
    #pragma unroll
    for (int r = 0; r < 12; ++r) {
        const int l = rg * 16 + r;
        const int gr = ((l >> 7) << 9) + (b << 7) + (l & 127);
        #pragma unroll
        for (int kk = 0; kk < 4; ++kk) {
            const int c = (((b + kk) & 3) << 4) + cg;   // h chunk index
            w[r][kk] = *(const uint4*)(w16u + rowbase + (size_t)gr * 256 + c * 4);
        }
    }
    #pragma unroll
    for (int r2 = 0; r2 < 4; ++r2) {
        const int l = rg * 16 + 12 + r2;
        const int gr = ((l >> 7) << 9) + (b << 7) + (l & 127);
        #pragma unroll
        for (int kk = 0; kk < 4; ++kk) {
            const int c  = (((b + kk) & 3) << 4) + cg;
            const int wc = (((kk + rg) & 3) << 4) + cg;  // bank-spread position
            *(uint4*)&w_lds[((rg * 4 + r2) * 64 + wc) * 4] =
                *(const uint4*)(w16u + rowbase + (size_t)gr * 256 + c * 4);
        }
    }

    // own output row (post-butterfly): l_own = rg*16 + rev4(cg)
    const int rev = ((cg & 1) << 3) | ((cg & 2) << 1) | ((cg & 4) >> 1) | ((cg & 8) >> 3);
    const int l_own = rg * 16 + rev;
    const int gr_own = ((l_own >> 7) << 9) + (b << 7) + (l_own & 127);
    const float wib_own  = W_ih[(size_t)m * G4 + gr_own];
    const float bias_own = b_ih[(size_t)m * G4 + gr_own] + b_hh[(size_t)m * G4 + gr_own];

    // roles: cell = tid<128 (1 elem each, waves 0-1); readers = tid 128..319
    const bool is_writer = (tid < 128);
    const bool is_reader = (tid >= 128 && tid < 320);
    const int  rr    = tid - 128;                    // 0..191
    const int  widx  = (((b + 1 + (rr >> 6)) & 3) << 6) + (rr & 63);  // pair idx

    float c0 = 0.0f;   // cell state, lives in tid<128

    if (tid < 256) h_pk[tid] = 0u;

    // prologue: h(0)=0 -> gates(t=0) are input+bias only
    gates_sh[l_own] = hist_sh[0] * wib_own + bias_own;

    for (int t = 0; t < TSTEPS - 1; ++t) {
        __syncthreads();   // gates_sh(t) ready
        const unsigned seq = (unsigned)(t + 1);
        const size_t pbase = (size_t)(seq & 1) * (NMOD * 256) + (size_t)m * 256;

        unsigned long long pv = 0;
        if (is_writer) {
            // cell update for h elem tid of my 128-segment
            const float gi = fsig(gates_sh[tid]);
            const float gf = fsig(gates_sh[128 + tid]);
            const float gg = ftanh_(gates_sh[256 + tid]);
            const float go = fsig(gates_sh[384 + tid]);
            c0 = gf * c0 + gi * gg;
            const float hv = go * ftanh_(c0);
            const float ho = __shfl_xor(hv, 1, 64);   // partner elem (intra-wave)
            if ((tid & 1) == 0) {
                __half2 hh = __floats2half2_rn(hv, ho);
                const unsigned pay = *reinterpret_cast<unsigned*>(&hh);
                const int word = tid >> 1;
                __hip_atomic_store(&hx[pbase + b * 64 + word],
                                   ((unsigned long long)seq << 32) | pay,
                                   __ATOMIC_RELAXED, __HIP_MEMORY_SCOPE_AGENT);
                h_pk[b * 64 + word] = pay;   // local pairs skip memory
            }
        } else if (is_reader) {
            // speculative first poll, overlapped with writers' cell phase
            pv = __hip_atomic_load(&hx[pbase + widx],
                                   __ATOMIC_RELAXED, __HIP_MEMORY_SCOPE_AGENT);
        }
        __syncthreads();   // local h_pk region valid

        // ---- kk=0: dots over LOCAL h region while remote h is in flight ----
        float acc[16];
        #pragma unroll
        for (int r = 0; r < 16; ++r) acc[r] = 0.0f;
        {
            const uint4 hq = *(const uint4*)&h_pk[(b << 6) + cg * 4];
            #pragma unroll
            for (int r = 0; r < 12; ++r) acc[r] = dot4(w[r][0], hq, acc[r]);
            const int wc0 = ((rg & 3) << 4) + cg;
            #pragma unroll
            for (int r2 = 0; r2 < 4; ++r2) {
                const uint4 lw = *(const uint4*)&w_lds[((rg * 4 + r2) * 64 + wc0) * 4];
                acc[12 + r2] = dot4(lw, hq, acc[12 + r2]);
            }
        }

        if (is_reader) {
            while ((unsigned)(pv >> 32) != seq)
                pv = __hip_atomic_load(&hx[pbase + widx],
                                       __ATOMIC_RELAXED, __HIP_MEMORY_SCOPE_AGENT);
            h_pk[widx] = (unsigned)pv;
        }
        __syncthreads();   // full h_pk valid

        // ---- kk=1..3: remote-region dots ----
        #pragma unroll
        for (int kk = 1; kk < 4; ++kk) {
            const uint4 hq = *(const uint4*)&h_pk[((((b + kk) & 3)) << 6) + cg * 4];
            #pragma unroll
            for (int r = 0; r < 12; ++r) acc[r] = dot4(w[r][kk], hq, acc[r]);
            const int wc = (((kk + rg) & 3) << 4) + cg;
            #pragma unroll
            for (int r2 = 0; r2 < 4; ++r2) {
                const uint4 lw = *(const uint4*)&w_lds[((rg * 4 + r2) * 64 + wc) * 4];
                acc[12 + r2] = dot4(lw, hq, acc[12 + r2]);
            }
        }

        // payload-halving butterfly: stages 1-2 DPP quad_perm, 3-4 shfl_xor
        #pragma unroll
        for (int k = 0; k < 8; ++k) {
            const float send = (cg & 1) ? acc[k] : acc[8 + k];
            const float recv = dppf<0xB1>(send);
            acc[k] = ((cg & 1) ? acc[8 + k] : acc[k]) + recv;
        }
        #pragma unroll
        for (int k = 0; k < 4; ++k) {
            const float send = (cg & 2) ? acc[k] : acc[4 + k];
            const float recv = dppf<0x4E>(send);
            acc[k] = ((cg & 2) ? acc[4 + k] : acc[k]) + recv;
        }
        #pragma unroll
        for (int k = 0; k < 2; ++k) {
            const float send = (cg & 4) ? acc[k] : acc[2 + k];
            const float recv = __shfl_xor(send, 4, 64);
            acc[k] = ((cg & 4) ? acc[2 + k] : acc[k]) + recv;
        }
        {
            const float send = (cg & 8) ? acc[0] : acc[1];
            const float recv = __shfl_xor(send, 8, 64);
            acc[0] = ((cg & 8) ? acc[1] : acc[0]) + recv;
        }

        gates_sh[l_own] = acc[0] + hist_sh[t + 1] * wib_own + bias_own;
    }

    // ---- epilogue: final cell update (t = TSTEPS-1) + one exchange ----
    __syncthreads();   // gates_sh(T-1) ready
    {
        const unsigned seq = (unsigned)TSTEPS;
        const size_t pbase = (size_t)(seq & 1) * (NMOD * 256) + (size_t)m * 256;
        if (is_writer) {
            const float gi = fsig(gates_sh[tid]);
            const float gf = fsig(gates_sh[128 + tid]);
            const float gg = ftanh_(gates_sh[256 + tid]);
            const float go = fsig(gates_sh[384 + tid]);
            c0 = gf * c0 + gi * gg;
            const float hv = go * ftanh_(c0);
            const float ho = __shfl_xor(hv, 1, 64);
            if ((tid & 1) == 0) {
                __half2 hh = __floats2half2_rn(hv, ho);
                const unsigned pay = *reinterpret_cast<unsigned*>(&hh);
                const int word = tid >> 1;
                __hip_atomic_store(&hx[pbase + b * 64 + word],
                                   ((unsigned long long)seq << 32) | pay,
                                   __ATOMIC_RELAXED, __HIP_MEMORY_SCOPE_AGENT);
                h_pk[b * 64 + word] = pay;
            }
        }
        if (b == 0) {
            if (is_reader) {
                unsigned long long pv;
                do {
                    pv = __hip_atomic_load(&hx[pbase + widx],
                                           __ATOMIC_RELAXED, __HIP_MEMORY_SCOPE_AGENT);
                } while ((unsigned)(pv >> 32) != seq);
                h_pk[widx] = (unsigned)pv;
            }
            __syncthreads();
            // per-module linear from f16 h
            float v = 0.0f;
            if (tid < 256) {
                const __half2 u = *reinterpret_cast<const __half2*>(&h_pk[tid]);
                const float* lwp = lin_W + (size_t)m * (HID + 1);
                v = __half2float(u.x) * lwp[2 * tid] + __half2float(u.y) * lwp[2 * tid + 1];
            }
            #pragma unroll
            for (int s2 = 32; s2; s2 >>= 1) v += __shfl_xor(v, s2, 64);
            if ((tid & 63) == 0) red_sh[tid >> 6] = v;
            __syncthreads();
            if (tid == 0) {
                float s = 0.0f;
                #pragma unroll
                for (int wv2 = 0; wv2 < 8; ++wv2) s += red_sh[wv2];
                s += recent[m] * lin_W[(size_t)m * (HID + 1) + HID] + lin_b[m];
                per_mod[m] = s;
            }
        }
    }
}

// ---------------- fallback: round-1 f32 single-block-per-module kernel -------
__global__ __launch_bounds__(1024) void lstm_module_kernel(
    const float* __restrict__ recent,
    const float* __restrict__ history,
    const float* __restrict__ W_ih,
    const float* __restrict__ W_hh,
    const float* __restrict__ b_ih,
    const float* __restrict__ b_hh,
    const float* __restrict__ lin_W,
    const float* __restrict__ lin_b,
    float* __restrict__ per_mod)
{
    const int n = blockIdx.x;
    const int tid = threadIdx.x;

    __shared__ float h_sh[HID];
    __shared__ float gates_sh[G4];
    __shared__ float wib_sh[G4];
    __shared__ float bias_sh[G4];
    __shared__ float hist_sh[TSTEPS];

    for (int i = tid; i < G4; i += 1024) {
        wib_sh[i]  = W_ih[(size_t)n * G4 + i];
        bias_sh[i] = b_ih[(size_t)n * G4 + i] + b_hh[(size_t)n * G4 + i];
    }
    for (int i = tid; i < TSTEPS; i += 1024) hist_sh[i] = history[(size_t)n * TSTEPS + i];
    if (tid < HID) h_sh[tid] = 0.0f;
    float c_reg = 0.0f;
    __syncthreads();

    const int sub = tid & 15;
    const int rid = tid >> 4;
    const float* Wbase = W_hh + (size_t)n * G4 * HID;

    for (int t = 0; t < TSTEPS; ++t) {
        const float x = hist_sh[t];
        float hreg[32];
        #pragma unroll
        for (int j = 0; j < 8; ++j) {
            const float4 hv = *reinterpret_cast<const float4*>(&h_sh[sub * 4 + j * 64]);
            hreg[4 * j + 0] = hv.x; hreg[4 * j + 1] = hv.y;
            hreg[4 * j + 2] = hv.z; hreg[4 * j + 3] = hv.w;
        }
        for (int p = 0; p < 32; ++p) {
            const int r = p * 64 + rid;
            const float* wr = Wbase + (size_t)r * HID + sub * 4;
            float acc = 0.0f;
            #pragma unroll
            for (int j = 0; j < 8; ++j) {
                const float4 wv = *reinterpret_cast<const float4*>(wr + j * 64);
                acc += wv.x * hreg[4*j+0] + wv.y * hreg[4*j+1]
                     + wv.z * hreg[4*j+2] + wv.w * hreg[4*j+3];
            }
            acc += __shfl_xor(acc, 1, 64);
            acc += __shfl_xor(acc, 2, 64);
            acc += __shfl_xor(acc, 4, 64);
            acc += __shfl_xor(acc, 8, 64);
            if (sub == 0) gates_sh[r] = acc + x * wib_sh[r] + bias_sh[r];
        }
        __syncthreads();
        if (tid < HID) {
            const float ig = fsig(gates_sh[tid]);
            const float fg = fsig(gates_sh[HID + tid]);
            const float gg = ftanh_(gates_sh[2 * HID + tid]);
            const float og = fsig(gates_sh[3 * HID + tid]);
            c_reg = fg * c_reg + ig * gg;
            h_sh[tid] = og * ftanh_(c_reg);
        }
        __syncthreads();
    }

    if (tid < HID) {
        float v = h_sh[tid] * lin_W[(size_t)n * (HID + 1) + tid];
        #pragma unroll
        for (int m2 = 32; m2; m2 >>= 1) v += __shfl_xor(v, m2, 64);
        if ((tid & 63) == 0) gates_sh[tid >> 6] = v;
    }
    __syncthreads();
    if (tid == 0) {
        float s = 0.0f;
        #pragma unroll
        for (int w = 0; w < HID / 64; ++w) s += gates_sh[w];
        s += recent[n] * lin_W[(size_t)n * (HID + 1) + HID] + lin_b[n];
        per_mod[n] = s;
    }
}

__global__ void finish_kernel(const float* __restrict__ per_mod,
                              const float* __restrict__ final_W,
                              const float* __restrict__ final_b,
                              float* __restrict__ out)
{
    const int l = threadIdx.x;
    float v = per_mod[l] * final_W[l];
    #pragma unroll
    for (int m = 32; m; m >>= 1) v += __shfl_xor(v, m, 64);
    if (l == 0) out[0] = v + final_b[0];
}

extern "C" void kernel_launch(void* const* d_in, const int* in_sizes, int n_in,
                              void* d_out, int out_size, void* d_ws, size_t ws_size,
                              hipStream_t stream) {
    const float* recent  = (const float*)d_in[0];
    const float* history = (const float*)d_in[1];
    const float* W_ih    = (const float*)d_in[2];
    const float* W_hh    = (const float*)d_in[3];
    const float* b_ih    = (const float*)d_in[4];
    const float* b_hh    = (const float*)d_in[5];
    const float* lin_W   = (const float*)d_in[6];
    const float* lin_b   = (const float*)d_in[7];
    const float* final_W = (const float*)d_in[8];
    const float* final_b = (const float*)d_in[9];
    float* out = (float*)d_out;
    float* per_mod = (float*)d_ws;

    if (ws_size >= WS_NEED) {
        __half* w16 = (__half*)((char*)d_ws + WOFF_W16);
        unsigned long long* hx = (unsigned long long*)((char*)d_ws + WOFF_HX);

        // zero per_mod + hx each call (ws is not re-poisoned between replays;
        // stale seq tags would alias across graph replays)
        hipMemsetAsync(d_ws, 0, WOFF_W16, stream);

        const int conv_blocks = (int)((size_t)NMOD * G4 * HID / 8 / 256);
        conv_kernel<<<conv_blocks, 256, 0, stream>>>(W_hh, w16);

        lstm_res_kernel<<<NMOD * 4, 512, 0, stream>>>(
            recent, history, W_ih, b_ih, b_hh, lin_W, lin_b,
            (const unsigned*)w16, hx, per_mod);
    } else {
        lstm_module_kernel<<<NMOD, 1024, 0, stream>>>(
            recent, history, W_ih, W_hh, b_ih, b_hh, lin_W, lin_b, per_mod);
    }
    finish_kernel<<<1, 64, 0, stream>>>(per_mod, final_W, final_b, out);
}